// Round 6
// baseline (451.507 us; speedup 1.0000x reference)
//
#include <hip/hip_runtime.h>

// ExplicitLiePE: y[b,s] = expm(A) @ x[b,s],  A = sum_k r[b,s,k] * 0.5*(L_k - L_k^T)
// (P_sp = identity in this config).
//
// One wave per token; lane i holds row i of 2*A/rho in 64 VGPRs.
// exp(A)x via Jacobi-Anger/Chebyshev + Clenshaw; Bessel coefficients by Miller
// backward recurrence fused into the Clenshaw loop (math verified R2-R5).
//
// R6 vs R5 (128 us, VGPR 204 -> 2 waves/SIMD, VALUBusy 35%):
//  - __launch_bounds__(512,4): VGPR cap 128. Safe now: R5 proved the inline,
//    non-address-taken form promotes row[] (spills in R3/R4 were caused by
//    passing row[64] by reference). TPB=512 / 8 tokens per block -> LDS 54.3 KB
//    -> 2 blocks/CU -> 16 waves/CU (2x R5).
//  - Hybrid t-broadcast split across pipes: 16 values via 4x ds_read_b128
//    (same-address broadcast, LDS pipe), 48 values via v_readlane (VALU pipe).
//    Readlane block issues first to cover the LDS write->read latency; only
//    4 float4s in flight keeps pressure under the 128 cap.

#define TPB 512
#define TOKENS_PER_BLOCK 8
#define LPAD 68                  // float stride: rows 16B-aligned for b128 LDS reads
                                 // (R1/R5 measured 0 conflicts); col reads lane-consecutive.
#define LSTRIDE (64 * LPAD)

__device__ __forceinline__ float bcast(float v, int l) {
    return __int_as_float(__builtin_amdgcn_readlane(__float_as_int(v), l));
}

__global__ __launch_bounds__(TPB, 4) void liepe_kernel(
    const float* __restrict__ x,
    const float* __restrict__ r_grid,
    const float* __restrict__ L_param,
    float* __restrict__ out,
    int n_tokens)
{
    __shared__ __align__(16) float Lsh[3 * LSTRIDE];
    __shared__ __align__(16) float tbuf[TOKENS_PER_BLOCK][64];

    // Stage raw L (3x64x64) into LDS, padded stride. Coalesced global reads.
    for (int idx = threadIdx.x; idx < 3 * 64 * 64; idx += TPB) {
        int k = idx >> 12;
        int rem = idx & 4095;
        int i = rem >> 6;
        int j = rem & 63;
        Lsh[k * LSTRIDE + i * LPAD + j] = L_param[idx];
    }
    __syncthreads();

    const int lane = threadIdx.x & 63;
    const int wid  = threadIdx.x >> 6;
    const int bs   = blockIdx.x * TOKENS_PER_BLOCK + wid;
    if (bs >= n_tokens) return;

    const float r0 = r_grid[bs * 3 + 0];
    const float r1 = r_grid[bs * 3 + 1];
    const float r2 = r_grid[bs * 3 + 2];

    const float sig2 = 0.5f * (r0 * r0 + r1 * r1 + r2 * r2);
    const float rho  = fmaf(16.4f, __builtin_sqrtf(sig2), 1.5f);
    const float inv_rho = 1.0f / rho;
    const int M = (int)rho + 12;

    // rows hold 2*A/rho: coefficient per generator = r_k / rho
    const float c0 = r0 * inv_rho;
    const float c1 = r1 * inv_rho;
    const float c2 = r2 * inv_rho;

    // Build row[j] = (2A/rho)[lane][j] = sum_k c_k * (L_k[lane][j] - L_k[j][lane])
    float row[64];
    #pragma unroll
    for (int j4 = 0; j4 < 64; j4 += 4) {
        float acc0 = 0.f, acc1 = 0.f, acc2 = 0.f, acc3 = 0.f;
        #pragma unroll
        for (int k = 0; k < 3; ++k) {
            const float ck = (k == 0) ? c0 : ((k == 1) ? c1 : c2);
            const float* base = &Lsh[k * LSTRIDE];
            float4 a = *(const float4*)(base + lane * LPAD + j4);
            float b0v = base[(j4 + 0) * LPAD + lane];
            float b1v = base[(j4 + 1) * LPAD + lane];
            float b2v = base[(j4 + 2) * LPAD + lane];
            float b3v = base[(j4 + 3) * LPAD + lane];
            acc0 = fmaf(ck, a.x - b0v, acc0);
            acc1 = fmaf(ck, a.y - b1v, acc1);
            acc2 = fmaf(ck, a.z - b2v, acc2);
            acc3 = fmaf(ck, a.w - b3v, acc3);
        }
        row[j4 + 0] = acc0;
        row[j4 + 1] = acc1;
        row[j4 + 2] = acc2;
        row[j4 + 3] = acc3;
    }

    const float xv = x[bs * 64 + lane];

    // ---- Miller backward recurrence for unnormalized Jm(rho), fused Clenshaw ----
    float jp = 0.f;          // J~_{m+1}
    float jc = 1e-12f;       // J~_{m}, starting at m = ms
    const int ms = M + 10;
    float N = ((ms & 1) == 0) ? (jc + jc) : 0.f;   // normalizer: J0 + 2*sum_even Jm

    for (int m = ms; m > M; --m) {
        float jm = fmaf((2.f * (float)m) * inv_rho, jc, -jp);  // J~_{m-1}
        jp = jc; jc = jm;
        int mm = m - 1;
        if ((mm & 1) == 0) N += (mm > 0) ? (jm + jm) : jm;
    }
    // jc = J~_M.  b_M = a_M * x = 2*J~_M * x
    float b1 = (jc + jc) * xv;
    float b2 = 0.f;
    {   // advance to J~_{M-1}
        float jm = fmaf((2.f * (float)M) * inv_rho, jc, -jp);
        jp = jc; jc = jm;
        int mm = M - 1;
        if ((mm & 1) == 0) N += (mm > 0) ? (jm + jm) : jm;
    }

    // Clenshaw: b_m = 2*J~_m * x + (2A/rho) b_{m+1} + b_{m+2}
    #pragma unroll 1
    for (int m = M - 1; m >= 0; --m) {
        tbuf[wid][lane] = b1;                    // ds_write_b32, conflict-free
        float a0 = 0.f, a1 = 0.f, a2 = 0.f, a3 = 0.f;
        // readlane half first (VALU pipe) — covers the LDS write->read latency
        #pragma unroll
        for (int j = 16; j < 64; j += 4) {
            float t0 = bcast(b1, j + 0);
            float t1 = bcast(b1, j + 1);
            float t2 = bcast(b1, j + 2);
            float t3 = bcast(b1, j + 3);
            a0 = fmaf(row[j + 0], t0, a0);
            a1 = fmaf(row[j + 1], t1, a1);
            a2 = fmaf(row[j + 2], t2, a2);
            a3 = fmaf(row[j + 3], t3, a3);
        }
        // LDS half: 4 same-address b128 broadcasts
        #pragma unroll
        for (int j4 = 0; j4 < 4; ++j4) {
            float4 t4 = *(const float4*)(&tbuf[wid][4 * j4]);
            a0 = fmaf(row[4 * j4 + 0], t4.x, a0);
            a1 = fmaf(row[4 * j4 + 1], t4.y, a1);
            a2 = fmaf(row[4 * j4 + 2], t4.z, a2);
            a3 = fmaf(row[4 * j4 + 3], t4.w, a3);
        }
        float t = (a0 + a1) + (a2 + a3);         // (2A/rho) b1
        if (m > 0) {
            float bn = fmaf(jc + jc, xv, t + b2);
            b2 = b1; b1 = bn;
            float jm = fmaf((2.f * (float)m) * inv_rho, jc, -jp);
            jp = jc; jc = jm;
            int mm = m - 1;
            if ((mm & 1) == 0) N += (mm > 0) ? (jm + jm) : jm;
        } else {
            // jc = J~_0 (already folded into N).
            // b0 = J~_0 x + (2A/rho) b1 + b2; result = (b0 - (A/rho) b1) / N.
            float b0 = fmaf(jc, xv, t + b2);
            float y  = (b0 - 0.5f * t) / N;
            out[bs * 64 + lane] = y;
        }
    }
}

extern "C" void kernel_launch(void* const* d_in, const int* in_sizes, int n_in,
                              void* d_out, int out_size, void* d_ws, size_t ws_size,
                              hipStream_t stream) {
    const float* x = (const float*)d_in[0];
    const float* r = (const float*)d_in[1];
    const float* L = (const float*)d_in[2];
    // d_in[3] = P_sp: identity (allow_mixing=False) -> R_eff = R_r.
    float* out = (float*)d_out;

    int n_tokens = in_sizes[0] / 64;  // B*S = 8192
    int grid = (n_tokens + TOKENS_PER_BLOCK - 1) / TOKENS_PER_BLOCK;
    liepe_kernel<<<grid, TPB, 0, stream>>>(x, r, L, out, n_tokens);
}

// Round 7
// 245.120 us; speedup vs baseline: 1.8420x; 1.8420x over previous
//
#include <hip/hip_runtime.h>

// ExplicitLiePE: y[b,s] = expm(A) @ x[b,s],  A = sum_k r[b,s,k] * 0.5*(L_k - L_k^T)
// (P_sp = identity in this config).
//
// One wave per token; lane i holds row i of 2*A/rho as 32 packed float2 in
// VGPRs. exp(A)x via Jacobi-Anger/Chebyshev + Clenshaw; Bessel coefficients by
// Miller backward recurrence fused into the Clenshaw loop (math verified R2-R6).
//
// R7 vs R5 (128 us, VGPR 204 -> 2 waves/SIMD, VALUBusy 35%):
//  - __launch_bounds__(256, 3): VGPR cap ~170. R6 proved cap=128 spills row[]
//    (hbm 1.3 GB); R5 proved uncapped wants 204 (pipelining temps). 170 trims
//    only scheduler temps, keeps the ~110-reg live set in VGPRs, and buys
//    3 blocks/CU = 12 waves/CU.
//  - Packed-FP32 matvec: v_pk_fma_f32 (2 FMA/lane/instr — required for the
//    157 TF fp32 rate) via __builtin_elementwise_fma on clang ext-vectors.
//    Per term: 16 same-address ds_read_b128 broadcasts (LDS pipe) + 32 pk_fma
//    (VALU) instead of 64 fma + 64 broadcast ops.

#define TPB 256
#define TOKENS_PER_BLOCK 4
#define LPAD 68                  // float stride: rows 16B-aligned for b128 LDS reads
                                 // (R1/R5 measured 0 conflicts); col reads lane-consecutive.
#define LSTRIDE (64 * LPAD)

typedef float v2f __attribute__((ext_vector_type(2)));
typedef float v4f __attribute__((ext_vector_type(4)));

__global__ __launch_bounds__(TPB, 3) void liepe_kernel(
    const float* __restrict__ x,
    const float* __restrict__ r_grid,
    const float* __restrict__ L_param,
    float* __restrict__ out,
    int n_tokens)
{
    __shared__ __align__(16) float Lsh[3 * LSTRIDE];
    __shared__ __align__(16) float tbuf[TOKENS_PER_BLOCK][64];

    // Stage raw L (3x64x64) into LDS, padded stride. Coalesced global reads.
    for (int idx = threadIdx.x; idx < 3 * 64 * 64; idx += TPB) {
        int k = idx >> 12;
        int rem = idx & 4095;
        int i = rem >> 6;
        int j = rem & 63;
        Lsh[k * LSTRIDE + i * LPAD + j] = L_param[idx];
    }
    __syncthreads();

    const int lane = threadIdx.x & 63;
    const int wid  = threadIdx.x >> 6;
    const int bs   = blockIdx.x * TOKENS_PER_BLOCK + wid;
    if (bs >= n_tokens) return;

    const float r0 = r_grid[bs * 3 + 0];
    const float r1 = r_grid[bs * 3 + 1];
    const float r2 = r_grid[bs * 3 + 2];

    const float sig2 = 0.5f * (r0 * r0 + r1 * r1 + r2 * r2);
    const float rho  = fmaf(16.4f, __builtin_sqrtf(sig2), 1.5f);
    const float inv_rho = 1.0f / rho;
    const int M = (int)rho + 12;

    // rows hold 2*A/rho: coefficient per generator = r_k / rho
    const float c0 = r0 * inv_rho;
    const float c1 = r1 * inv_rho;
    const float c2 = r2 * inv_rho;

    // Build row2[j2] = (2A/rho)[lane][2*j2 .. 2*j2+1] packed as float2.
    v2f row2[32];
    #pragma unroll
    for (int j4 = 0; j4 < 64; j4 += 4) {
        float acc0 = 0.f, acc1 = 0.f, acc2 = 0.f, acc3 = 0.f;
        #pragma unroll
        for (int k = 0; k < 3; ++k) {
            const float ck = (k == 0) ? c0 : ((k == 1) ? c1 : c2);
            const float* base = &Lsh[k * LSTRIDE];
            v4f a = *(const v4f*)(base + lane * LPAD + j4);
            float b0v = base[(j4 + 0) * LPAD + lane];
            float b1v = base[(j4 + 1) * LPAD + lane];
            float b2v = base[(j4 + 2) * LPAD + lane];
            float b3v = base[(j4 + 3) * LPAD + lane];
            acc0 = fmaf(ck, a.x - b0v, acc0);
            acc1 = fmaf(ck, a.y - b1v, acc1);
            acc2 = fmaf(ck, a.z - b2v, acc2);
            acc3 = fmaf(ck, a.w - b3v, acc3);
        }
        v2f lo, hi;
        lo.x = acc0; lo.y = acc1;
        hi.x = acc2; hi.y = acc3;
        row2[(j4 >> 1) + 0] = lo;
        row2[(j4 >> 1) + 1] = hi;
    }

    const float xv = x[bs * 64 + lane];

    // ---- Miller backward recurrence for unnormalized Jm(rho), fused Clenshaw ----
    float jp = 0.f;          // J~_{m+1}
    float jc = 1e-12f;       // J~_{m}, starting at m = ms
    const int ms = M + 10;
    float N = ((ms & 1) == 0) ? (jc + jc) : 0.f;   // normalizer: J0 + 2*sum_even Jm

    for (int m = ms; m > M; --m) {
        float jm = fmaf((2.f * (float)m) * inv_rho, jc, -jp);  // J~_{m-1}
        jp = jc; jc = jm;
        int mm = m - 1;
        if ((mm & 1) == 0) N += (mm > 0) ? (jm + jm) : jm;
    }
    // jc = J~_M.  b_M = a_M * x = 2*J~_M * x
    float b1 = (jc + jc) * xv;
    float b2 = 0.f;
    {   // advance to J~_{M-1}
        float jm = fmaf((2.f * (float)M) * inv_rho, jc, -jp);
        jp = jc; jc = jm;
        int mm = M - 1;
        if ((mm & 1) == 0) N += (mm > 0) ? (jm + jm) : jm;
    }

    // Clenshaw: b_m = 2*J~_m * x + (2A/rho) b_{m+1} + b_{m+2}
    #pragma unroll 1
    for (int m = M - 1; m >= 0; --m) {
        tbuf[wid][lane] = b1;                    // ds_write_b32, conflict-free
        v2f a0 = {0.f, 0.f}, a1 = {0.f, 0.f}, a2 = {0.f, 0.f}, a3 = {0.f, 0.f};
        #pragma unroll
        for (int j4 = 0; j4 < 16; j4 += 2) {
            v4f t4a = *(const v4f*)(&tbuf[wid][4 * j4]);      // broadcast read
            v4f t4b = *(const v4f*)(&tbuf[wid][4 * j4 + 4]);  // broadcast read
            a0 = __builtin_elementwise_fma(row2[2 * j4 + 0], t4a.xy, a0);
            a1 = __builtin_elementwise_fma(row2[2 * j4 + 1], t4a.zw, a1);
            a2 = __builtin_elementwise_fma(row2[2 * j4 + 2], t4b.xy, a2);
            a3 = __builtin_elementwise_fma(row2[2 * j4 + 3], t4b.zw, a3);
        }
        v2f s = (a0 + a1) + (a2 + a3);
        float t = s.x + s.y;                     // (2A/rho) b1
        if (m > 0) {
            float bn = fmaf(jc + jc, xv, t + b2);
            b2 = b1; b1 = bn;
            float jm = fmaf((2.f * (float)m) * inv_rho, jc, -jp);
            jp = jc; jc = jm;
            int mm = m - 1;
            if ((mm & 1) == 0) N += (mm > 0) ? (jm + jm) : jm;
        } else {
            // jc = J~_0 (already folded into N).
            // b0 = J~_0 x + (2A/rho) b1 + b2; result = (b0 - (A/rho) b1) / N.
            float b0 = fmaf(jc, xv, t + b2);
            float y  = (b0 - 0.5f * t) / N;
            out[bs * 64 + lane] = y;
        }
    }
}

extern "C" void kernel_launch(void* const* d_in, const int* in_sizes, int n_in,
                              void* d_out, int out_size, void* d_ws, size_t ws_size,
                              hipStream_t stream) {
    const float* x = (const float*)d_in[0];
    const float* r = (const float*)d_in[1];
    const float* L = (const float*)d_in[2];
    // d_in[3] = P_sp: identity (allow_mixing=False) -> R_eff = R_r.
    float* out = (float*)d_out;

    int n_tokens = in_sizes[0] / 64;  // B*S = 8192
    int grid = (n_tokens + TOKENS_PER_BLOCK - 1) / TOKENS_PER_BLOCK;
    liepe_kernel<<<grid, TPB, 0, stream>>>(x, r, L, out, n_tokens);
}